// Round 6
// baseline (327.032 us; speedup 1.0000x reference)
//
#include <hip/hip_runtime.h>
#include <hip/hip_bf16.h>

typedef __bf16 bf16x8 __attribute__((ext_vector_type(8)));
typedef float  f32x4  __attribute__((ext_vector_type(4)));
typedef float  f32x16 __attribute__((ext_vector_type(16)));

#define MFMA16(a, b, c) __builtin_amdgcn_mfma_f32_16x16x32_bf16((a), (b), (c), 0, 0, 0)
#define MFMA32(a, b, c) __builtin_amdgcn_mfma_f32_32x32x16_bf16((a), (b), (c), 0, 0, 0)

__device__ __forceinline__ float fast_exp2(float x) {
#if __has_builtin(__builtin_amdgcn_exp2f)
    return __builtin_amdgcn_exp2f(x);
#else
    return exp2f(x);
#endif
}

// async global->LDS, 16B per lane; lds base must be wave-uniform (HW adds lane*16).
__device__ __forceinline__ void async16(void* lds, const void* g) {
    __builtin_amdgcn_global_load_lds(
        (const __attribute__((address_space(1))) unsigned int*)g,
        (__attribute__((address_space(3))) unsigned int*)lds, 16, 0, 0);
}

// ---------------- fused transpose+convert: 6 jobs, W[K,N] f32 -> WT[N,K] bf16 ----------------
__device__ __forceinline__ void tconv_tile(const float* __restrict__ W,
                                           __bf16* __restrict__ WT,
                                           int K, int N, int id, int nbx,
                                           __bf16 (*t)[65]) {
    int n0 = (id % nbx) * 64, k0 = (id / nbx) * 64;
    int tx = threadIdx.x & 63, ty = threadIdx.x >> 6;
#pragma unroll
    for (int r = ty; r < 64; r += 4)
        t[r][tx] = (__bf16)W[(size_t)(k0 + r) * N + n0 + tx];
    __syncthreads();
#pragma unroll
    for (int rr = ty; rr < 64; rr += 4)
        WT[(size_t)(n0 + rr) * K + k0 + tx] = t[tx][rr];
}

__global__ __launch_bounds__(256) void tconv6_kernel(
    const float* W0, __bf16* T0, const float* W1, __bf16* T1,
    const float* W2, __bf16* T2, const float* W3, __bf16* T3,
    const float* W4, __bf16* T4, const float* W5, __bf16* T5) {
    __shared__ __bf16 t[64][65];
    int id = blockIdx.x;
    if (id < 128)      tconv_tile(W0, T0, 1024, 512,  id,       8,  t);
    else if (id < 384) tconv_tile(W1, T1, 1024, 1024, id - 128, 16, t);
    else if (id < 512) tconv_tile(W2, T2, 512,  1024, id - 384, 16, t);
    else if (id < 640) tconv_tile(W3, T3, 1024, 512,  id - 512, 8,  t);
    else if (id < 832) tconv_tile(W4, T4, 768,  1024, id - 640, 16, t);
    else               tconv_tile(W5, T5, 512,  1024, id - 832, 16, t);
}

// ---------------- LayerNorm body ----------------
template <int C>
__device__ __forceinline__ void ln_body(const float* __restrict__ xr,
                                        const float* __restrict__ g,
                                        const float* __restrict__ b,
                                        __bf16* __restrict__ orow,
                                        float* p1, float* p2) {
    constexpr int NP = (C == 1024) ? 4 : 3;
    float v[NP], s1 = 0.f, s2 = 0.f;
    if constexpr (C == 1024) {
        float4 f = *(const float4*)&xr[threadIdx.x * 4];
        v[0] = f.x; v[1] = f.y; v[2] = f.z; v[3] = f.w;
#pragma unroll
        for (int i = 0; i < 4; i++) { s1 += v[i]; s2 += v[i] * v[i]; }
    } else {
#pragma unroll
        for (int i = 0; i < 3; i++) {
            v[i] = xr[threadIdx.x + i * 256];
            s1 += v[i]; s2 += v[i] * v[i];
        }
    }
#pragma unroll
    for (int off = 1; off < 64; off <<= 1) {
        s1 += __shfl_xor(s1, off);
        s2 += __shfl_xor(s2, off);
    }
    int wave = threadIdx.x >> 6;
    if ((threadIdx.x & 63) == 0) { p1[wave] = s1; p2[wave] = s2; }
    __syncthreads();
    s1 = p1[0] + p1[1] + p1[2] + p1[3];
    s2 = p2[0] + p2[1] + p2[2] + p2[3];
    float mean = s1 / C;
    float rstd = rsqrtf(s2 / C - mean * mean + 1e-5f);
    if constexpr (C == 1024) {
        union { __bf16 h[4]; unsigned long long u; } pk;
#pragma unroll
        for (int i = 0; i < 4; i++) {
            int c = threadIdx.x * 4 + i;
            pk.h[i] = (__bf16)((v[i] - mean) * rstd * g[c] + b[c]);
        }
        *(unsigned long long*)&orow[threadIdx.x * 4] = pk.u;
    } else {
#pragma unroll
        for (int i = 0; i < 3; i++) {
            int c = threadIdx.x + i * 256;
            orow[c] = (__bf16)((v[i] - mean) * rstd * g[c] + b[c]);
        }
    }
}

__global__ __launch_bounds__(256) void ln2_kernel(const float* __restrict__ x,
                                                  const float* __restrict__ g1,
                                                  const float* __restrict__ b1,
                                                  const float* __restrict__ g2,
                                                  const float* __restrict__ b2,
                                                  __bf16* __restrict__ o1,
                                                  __bf16* __restrict__ o2) {
    constexpr int C = 1024;
    int row = blockIdx.x;
    const float* xr = x + (size_t)row * C;
    float4 f = *(const float4*)&xr[threadIdx.x * 4];
    float v[4] = {f.x, f.y, f.z, f.w};
    float s1 = 0.f, s2 = 0.f;
#pragma unroll
    for (int i = 0; i < 4; i++) { s1 += v[i]; s2 += v[i] * v[i]; }
#pragma unroll
    for (int off = 1; off < 64; off <<= 1) {
        s1 += __shfl_xor(s1, off);
        s2 += __shfl_xor(s2, off);
    }
    __shared__ float p1[4], p2[4];
    int wave = threadIdx.x >> 6;
    if ((threadIdx.x & 63) == 0) { p1[wave] = s1; p2[wave] = s2; }
    __syncthreads();
    s1 = p1[0] + p1[1] + p1[2] + p1[3];
    s2 = p2[0] + p2[1] + p2[2] + p2[3];
    float mean = s1 / C;
    float rstd = rsqrtf(s2 / C - mean * mean + 1e-5f);
    union { __bf16 h[4]; unsigned long long u; } pk1, pk2;
#pragma unroll
    for (int i = 0; i < 4; i++) {
        int c = threadIdx.x * 4 + i;
        float nv = (v[i] - mean) * rstd;
        pk1.h[i] = (__bf16)(nv * g1[c] + b1[c]);
        pk2.h[i] = (__bf16)(nv * g2[c] + b2[c]);
    }
    *(unsigned long long*)&o1[(size_t)row * C + threadIdx.x * 4] = pk1.u;
    *(unsigned long long*)&o2[(size_t)row * C + threadIdx.x * 4] = pk2.u;
}

__global__ __launch_bounds__(256) void ln_cross_kernel(
    const float* __restrict__ x1, const float* __restrict__ g1, const float* __restrict__ b1,
    __bf16* __restrict__ o1,
    const float* __restrict__ ctx, const float* __restrict__ g2, const float* __restrict__ b2,
    __bf16* __restrict__ o2, int rows1) {
    __shared__ float p1[4], p2[4];
    int id = blockIdx.x;
    if (id < rows1) {
        ln_body<1024>(x1 + (size_t)id * 1024, g1, b1, o1 + (size_t)id * 1024, p1, p2);
    } else {
        int row = id - rows1;
        ln_body<768>(ctx + (size_t)row * 768, g2, b2, o2 + (size_t)row * 768, p1, p2);
    }
}

// ---------------- GEMM core (BK=64): C[M,N] = A[M,K] @ BT[N,K]^T ----------------
template <int EPI>
__device__ __forceinline__ void gemm_core(const __bf16* __restrict__ A,
                                          const __bf16* __restrict__ BT,
                                          void* __restrict__ Cout,
                                          int N, int K, int bm, int bn,
                                          const float* __restrict__ bias,
                                          const float* __restrict__ res,
                                          float scale,
                                          __bf16* Al, __bf16* Bl) {
    int tid = threadIdx.x;
    int lane = tid & 63, wave = tid >> 6;
    int quad = lane >> 4, l15 = lane & 15;
    int wm = wave >> 1, wn = wave & 1;
    const __bf16* Ab = A + (size_t)(bm * 128) * K;
    const __bf16* Bb = BT + (size_t)(bn * 128) * K;
    f32x4 acc[4][4] = {};
    for (int k0 = 0; k0 < K; k0 += 64) {
#pragma unroll
        for (int j = 0; j < 4; j++) {
            int sbase = wave * 256 + j * 64;
            int s = sbase + lane;
            int r = s >> 3, c = (s & 7) ^ (r & 7);
            async16((char*)Al + sbase * 16, &Ab[(size_t)r * K + k0 + c * 8]);
            async16((char*)Bl + sbase * 16, &Bb[(size_t)r * K + k0 + c * 8]);
        }
        __syncthreads();
#pragma unroll
        for (int ks = 0; ks < 2; ks++) {
            bf16x8 a[4], b[4];
#pragma unroll
            for (int i = 0; i < 4; i++) {
                int row = wm * 64 + i * 16 + l15;
                a[i] = *(const bf16x8*)&Al[row * 64 + ((ks * 4 + quad) ^ (row & 7)) * 8];
            }
#pragma unroll
            for (int t = 0; t < 4; t++) {
                int row = wn * 64 + t * 16 + l15;
                b[t] = *(const bf16x8*)&Bl[row * 64 + ((ks * 4 + quad) ^ (row & 7)) * 8];
            }
#pragma unroll
            for (int i = 0; i < 4; i++)
#pragma unroll
                for (int t = 0; t < 4; t++) acc[i][t] = MFMA16(a[i], b[t], acc[i][t]);
        }
        __syncthreads();
    }
#pragma unroll
    for (int i = 0; i < 4; i++) {
#pragma unroll
        for (int t = 0; t < 4; t++) {
#pragma unroll
            for (int r = 0; r < 4; r++) {
                int row = bm * 128 + wm * 64 + i * 16 + quad * 4 + r;
                int col = bn * 128 + wn * 64 + t * 16 + l15;
                float vv = acc[i][t][r];
                if (EPI == 0) {
                    ((__bf16*)Cout)[(size_t)row * N + col] = (__bf16)(vv * scale);
                } else {
                    ((float*)Cout)[(size_t)row * N + col] =
                        vv + bias[col] + res[(size_t)row * N + col];
                }
            }
        }
    }
}

template <int EPI>
__global__ __launch_bounds__(256) void gemm_bt(const __bf16* __restrict__ A,
                                               const __bf16* __restrict__ BT,
                                               void* __restrict__ Cout,
                                               int M, int N, int K,
                                               const float* __restrict__ bias,
                                               const float* __restrict__ res) {
    __shared__ __align__(16) __bf16 Al[128 * 64];
    __shared__ __align__(16) __bf16 Bl[128 * 64];
    gemm_core<EPI>(A, BT, Cout, N, K, blockIdx.x, blockIdx.y, bias, res, 1.0f, Al, Bl);
}

__global__ __launch_bounds__(256) void gemm_fused3(
    const __bf16* A0, const __bf16* B0, __bf16* C0, int N0, int K0, int nbn0, float sc0,
    const __bf16* A1, const __bf16* B1, __bf16* C1, int N1, int K1, int nbn1, float sc1,
    const __bf16* A2, const __bf16* B2, __bf16* C2, int N2, int K2, int nbn2, float sc2,
    int c0, int c1) {
    __shared__ __align__(16) __bf16 Al[128 * 64];
    __shared__ __align__(16) __bf16 Bl[128 * 64];
    int id = blockIdx.x;
    if (id < c0) {
        gemm_core<0>(A0, B0, C0, N0, K0, id / nbn0, id % nbn0, nullptr, nullptr, sc0, Al, Bl);
    } else if (id < c1) {
        id -= c0;
        gemm_core<0>(A1, B1, C1, N1, K1, id / nbn1, id % nbn1, nullptr, nullptr, sc1, Al, Bl);
    } else {
        id -= c1;
        gemm_core<0>(A2, B2, C2, N2, K2, id / nbn2, id % nbn2, nullptr, nullptr, sc2, Al, Bl);
    }
}

// ---------------- flash attention v2: 2-wave blocks, q-tile 128, 32x32x16 MFMA ----------------
// q (pre-scaled by 0.125*log2e): [B*n, 512]; kb: [B*m, 512]; vt: [512, B*m]; out: [B*n, 512]
// Wave w owns q rows [64w, 64w+64). St = K@Q^T in 32x32 C-layout:
//   col = q = 64w + 32nt + (lane&31); row = kv = 32mt + 4*l5 + (reg&3) + 8*(reg>>2).
// PV B-frag (k=kv=8*l5+j) assembled from St regs via shfl_xor(32) exchange — P never hits LDS.
__global__ __launch_bounds__(128) void flash_kernel(const __bf16* __restrict__ q,
                                                    const __bf16* __restrict__ kb,
                                                    const __bf16* __restrict__ vt,
                                                    __bf16* __restrict__ out,
                                                    int n, int m) {
    __shared__ __align__(16) __bf16 Qs[128 * 64];
    __shared__ __align__(16) __bf16 Ks[64 * 64];
    __shared__ __align__(16) __bf16 VTs[64 * 64];
    int tid = threadIdx.x;
    int lane = tid & 63, w = tid >> 6;      // 2 waves
    int l31 = lane & 31, l5 = lane >> 5;
    int qt = blockIdx.x, h = blockIdx.y, b = blockIdx.z;
    const size_t BM = (size_t)gridDim.z * m;

    // stage Q tile 128x64 (16B chunks, chunk c at slot c^(r&7))
#pragma unroll
    for (int j = 0; j < 8; j++) {
        int sbase = w * 512 + j * 64;
        int s = sbase + lane;
        int r = s >> 3, c = (s & 7) ^ (r & 7);
        async16((char*)Qs + sbase * 16,
                &q[(size_t)(b * n + qt * 128 + r) * 512 + h * 64 + c * 8]);
    }

    f32x16 acc[2][2] = {};    // O^T tiles [mt_d][nt]
    float l_acc[2] = {0.f, 0.f};

    int nkt = m / 64;
    for (int kt = 0; kt < nkt; kt++) {
#pragma unroll
        for (int j = 0; j < 4; j++) {
            int sbase = w * 256 + j * 64;
            int s = sbase + lane;
            int r = s >> 3, c = (s & 7) ^ (r & 7);
            async16((char*)Ks + sbase * 16,
                    &kb[(size_t)(b * m + kt * 64 + r) * 512 + h * 64 + c * 8]);
            async16((char*)VTs + sbase * 16,
                    &vt[(size_t)(h * 64 + r) * BM + b * m + kt * 64 + c * 8]);
        }
        __syncthreads();

#pragma unroll
        for (int mt = 0; mt < 2; mt++) {
            // ---- QK: St[kv = 32mt..+31][q = 64w..+63], K-depth d=64 ----
            f32x16 sacc[2] = {};
#pragma unroll
            for (int c = 0; c < 4; c++) {
                int krow = mt * 32 + l31;
                bf16x8 ak = *(const bf16x8*)&Ks[krow * 64 + ((2 * c + l5) ^ (krow & 7)) * 8];
#pragma unroll
                for (int nt = 0; nt < 2; nt++) {
                    int qrow = w * 64 + nt * 32 + l31;
                    bf16x8 bq = *(const bf16x8*)&Qs[qrow * 64 + ((2 * c + l5) ^ (qrow & 7)) * 8];
                    sacc[nt] = MFMA32(ak, bq, sacc[nt]);
                }
            }
            // ---- exp2, accumulate l, pack to bf16, lane<->lane^32 exchange ----
            unsigned long long pk[2][4], sh[2][4];
#pragma unroll
            for (int nt = 0; nt < 2; nt++) {
#pragma unroll
                for (int s = 0; s < 4; s++) {
                    float e0 = fast_exp2(sacc[nt][s * 4 + 0]);
                    float e1 = fast_exp2(sacc[nt][s * 4 + 1]);
                    float e2 = fast_exp2(sacc[nt][s * 4 + 2]);
                    float e3 = fast_exp2(sacc[nt][s * 4 + 3]);
                    l_acc[nt] += (e0 + e1) + (e2 + e3);
                    union { __bf16 hh[4]; unsigned long long u; } u;
                    u.hh[0] = (__bf16)e0; u.hh[1] = (__bf16)e1;
                    u.hh[2] = (__bf16)e2; u.hh[3] = (__bf16)e3;
                    pk[nt][s] = u.u;
                }
#pragma unroll
                for (int s = 0; s < 4; s++)
                    sh[nt][s] = __shfl_xor((unsigned long long)pk[nt][s], 32);
            }
            // ---- PV for kv k-steps c2 = 0,1 within this mt block ----
#pragma unroll
            for (int c2 = 0; c2 < 2; c2++) {
#pragma unroll
                for (int nt = 0; nt < 2; nt++) {
                    int s0 = 2 * c2, s1 = 2 * c2 + 1;
                    unsigned long long h0 = (l5 == 0) ? pk[nt][s0] : sh[nt][s1];
                    unsigned long long h1 = (l5 == 0) ? sh[nt][s0] : pk[nt][s1];
                    union { unsigned long long u[2]; bf16x8 v; } bu;
                    bu.u[0] = h0; bu.u[1] = h1;
#pragma unroll
                    for (int mtd = 0; mtd < 2; mtd++) {
                        int drow = mtd * 32 + l31;
                        int kchunk = 2 * (2 * mt + c2) + l5;
                        bf16x8 av = *(const bf16x8*)&VTs[drow * 64 + (kchunk ^ (drow & 7)) * 8];
                        acc[mtd][nt] = MFMA32(av, bu.v, acc[mtd][nt]);
                    }
                }
            }
        }
        __syncthreads();
    }

    // finalize: l(q) lives in lanes l and l^32
    float linv[2];
#pragma unroll
    for (int nt = 0; nt < 2; nt++) {
        float tot = l_acc[nt] + __shfl_xor(l_acc[nt], 32);
        linv[nt] = 1.0f / tot;
    }
#pragma unroll
    for (int nt = 0; nt < 2; nt++) {
        size_t qrow = (size_t)(b * n + qt * 128 + w * 64 + nt * 32 + l31);
#pragma unroll
        for (int mtd = 0; mtd < 2; mtd++) {
#pragma unroll
            for (int s = 0; s < 4; s++) {
                union { __bf16 hh[4]; unsigned long long u; } u;
#pragma unroll
                for (int r = 0; r < 4; r++)
                    u.hh[r] = (__bf16)(acc[mtd][nt][s * 4 + r] * linv[nt]);
                int d = mtd * 32 + s * 8 + l5 * 4;
                *(unsigned long long*)&out[qrow * 512 + h * 64 + d] = u.u;
            }
        }
    }
}

extern "C" void kernel_launch(void* const* d_in, const int* in_sizes, int n_in,
                              void* d_out, int out_size, void* d_ws, size_t ws_size,
                              hipStream_t stream) {
    const float* x      = (const float*)d_in[0];
    const float* ctx    = (const float*)d_in[1];
    const float* sa_ng  = (const float*)d_in[2];
    const float* sa_nb  = (const float*)d_in[3];
    const float* sa_ncg = (const float*)d_in[4];
    const float* sa_ncb = (const float*)d_in[5];
    const float* sa_wq  = (const float*)d_in[6];
    const float* sa_wkv = (const float*)d_in[7];
    const float* sa_wo  = (const float*)d_in[8];
    const float* sa_bo  = (const float*)d_in[9];
    const float* ca_ng  = (const float*)d_in[10];
    const float* ca_nb  = (const float*)d_in[11];
    const float* ca_ncg = (const float*)d_in[12];
    const float* ca_ncb = (const float*)d_in[13];
    const float* ca_wq  = (const float*)d_in[14];
    const float* ca_wkv = (const float*)d_in[15];
    const float* ca_wo  = (const float*)d_in[16];
    const float* ca_bo  = (const float*)d_in[17];
    float* out = (float*)d_out;

    const int B = 4, N = 2048, M = 512, F = 1024, CF = 768, MID = 512;
    const int ROWS = B * N;   // 8192
    const int CROWS = B * M;  // 2048
    const float QSCALE = 0.125f * 1.4426950408889634f;

    char* ws = (char*)d_ws;
    size_t off = 0;
    auto alloc = [&](size_t bytes) {
        void* p = ws + off;
        off = (off + bytes + 255) & ~(size_t)255;
        return p;
    };
    __bf16* wqT   = (__bf16*)alloc((size_t)MID * F * 2);
    __bf16* wkvT  = (__bf16*)alloc((size_t)(2 * MID) * F * 2);
    __bf16* woT   = (__bf16*)alloc((size_t)F * MID * 2);
    __bf16* cwqT  = (__bf16*)alloc((size_t)MID * F * 2);
    __bf16* cwkvT = (__bf16*)alloc((size_t)(2 * MID) * CF * 2);
    __bf16* cwoT  = (__bf16*)alloc((size_t)F * MID * 2);
    __bf16* xn1   = (__bf16*)alloc((size_t)ROWS * F * 2);
    __bf16* xn2   = (__bf16*)alloc((size_t)ROWS * F * 2);
    __bf16* qb    = (__bf16*)alloc((size_t)ROWS * MID * 2);
    __bf16* kb    = (__bf16*)alloc((size_t)ROWS * MID * 2);
    __bf16* vt    = (__bf16*)alloc((size_t)MID * ROWS * 2);
    __bf16* ao    = (__bf16*)alloc((size_t)ROWS * MID * 2);
    float*  x1    = (float*)alloc((size_t)ROWS * F * 4);
    (void)ws_size; (void)in_sizes; (void)n_in; (void)out_size;

    dim3 blk(256);
    dim3 fblk(128);

    tconv6_kernel<<<dim3(960), blk, 0, stream>>>(
        sa_wq, wqT, sa_wkv, wkvT, sa_wo, woT, ca_wq, cwqT, ca_wkv, cwkvT, ca_wo, cwoT);

    // ---- self-attention ----
    ln2_kernel<<<dim3(ROWS), blk, 0, stream>>>(x, sa_ng, sa_nb, sa_ncg, sa_ncb, xn1, xn2);
    {
        int c0 = (ROWS / 128) * (MID / 128);
        int c1 = c0 + (ROWS / 128) * (MID / 128);
        int c2 = c1 + (MID / 128) * (ROWS / 128);
        gemm_fused3<<<dim3(c2), blk, 0, stream>>>(
            xn1, wqT, qb, MID, F, MID / 128, QSCALE,
            xn2, wkvT, kb, MID, F, MID / 128, 1.0f,
            wkvT + (size_t)MID * F, xn2, vt, ROWS, F, ROWS / 128, 1.0f,
            c0, c1);
    }
    flash_kernel<<<dim3(N / 128, 8, B), fblk, 0, stream>>>(qb, kb, vt, ao, N, N);
    gemm_bt<1><<<dim3(ROWS / 128, F / 128), blk, 0, stream>>>(
        ao, woT, x1, ROWS, F, MID, sa_bo, x);

    // ---- cross-attention ----
    ln_cross_kernel<<<dim3(ROWS + CROWS), blk, 0, stream>>>(
        x1, ca_ng, ca_nb, xn1, ctx, ca_ncg, ca_ncb, xn2, ROWS);
    {
        int c0 = (ROWS / 128) * (MID / 128);
        int c1 = c0 + (CROWS / 128) * (MID / 128);
        int c2 = c1 + (MID / 128) * (CROWS / 128);
        gemm_fused3<<<dim3(c2), blk, 0, stream>>>(
            xn1, cwqT, qb, MID, F, MID / 128, QSCALE,
            xn2, cwkvT, kb, MID, CF, MID / 128, 1.0f,
            cwkvT + (size_t)MID * CF, xn2, vt, CROWS, CF, CROWS / 128, 1.0f,
            c0, c1);
    }
    flash_kernel<<<dim3(N / 128, 8, B), fblk, 0, stream>>>(qb, kb, vt, ao, N, M);
    gemm_bt<1><<<dim3(ROWS / 128, F / 128), blk, 0, stream>>>(
        ao, cwoT, out, ROWS, F, MID, ca_bo, x1);
}

// Round 7
// 324.315 us; speedup vs baseline: 1.0084x; 1.0084x over previous
//
#include <hip/hip_runtime.h>
#include <hip/hip_bf16.h>

typedef __bf16 bf16x8 __attribute__((ext_vector_type(8)));
typedef float  f32x4  __attribute__((ext_vector_type(4)));
typedef float  f32x16 __attribute__((ext_vector_type(16)));

#define MFMA16(a, b, c) __builtin_amdgcn_mfma_f32_16x16x32_bf16((a), (b), (c), 0, 0, 0)
#define MFMA32(a, b, c) __builtin_amdgcn_mfma_f32_32x32x16_bf16((a), (b), (c), 0, 0, 0)

__device__ __forceinline__ float fast_exp2(float x) {
#if __has_builtin(__builtin_amdgcn_exp2f)
    return __builtin_amdgcn_exp2f(x);
#else
    return exp2f(x);
#endif
}

// async global->LDS, 16B per lane; lds base must be wave-uniform (HW adds lane*16).
__device__ __forceinline__ void async16(void* lds, const void* g) {
    __builtin_amdgcn_global_load_lds(
        (const __attribute__((address_space(1))) unsigned int*)g,
        (__attribute__((address_space(3))) unsigned int*)lds, 16, 0, 0);
}

// ---------------- fused transpose+convert: 6 jobs, W[K,N] f32 -> WT[N,K] bf16 ----------------
__device__ __forceinline__ void tconv_tile(const float* __restrict__ W,
                                           __bf16* __restrict__ WT,
                                           int K, int N, int id, int nbx,
                                           __bf16 (*t)[65]) {
    int n0 = (id % nbx) * 64, k0 = (id / nbx) * 64;
    int tx = threadIdx.x & 63, ty = threadIdx.x >> 6;
#pragma unroll
    for (int r = ty; r < 64; r += 4)
        t[r][tx] = (__bf16)W[(size_t)(k0 + r) * N + n0 + tx];
    __syncthreads();
#pragma unroll
    for (int rr = ty; rr < 64; rr += 4)
        WT[(size_t)(n0 + rr) * K + k0 + tx] = t[tx][rr];
}

__global__ __launch_bounds__(256) void tconv6_kernel(
    const float* W0, __bf16* T0, const float* W1, __bf16* T1,
    const float* W2, __bf16* T2, const float* W3, __bf16* T3,
    const float* W4, __bf16* T4, const float* W5, __bf16* T5) {
    __shared__ __bf16 t[64][65];
    int id = blockIdx.x;
    if (id < 128)      tconv_tile(W0, T0, 1024, 512,  id,       8,  t);
    else if (id < 384) tconv_tile(W1, T1, 1024, 1024, id - 128, 16, t);
    else if (id < 512) tconv_tile(W2, T2, 512,  1024, id - 384, 16, t);
    else if (id < 640) tconv_tile(W3, T3, 1024, 512,  id - 512, 8,  t);
    else if (id < 832) tconv_tile(W4, T4, 768,  1024, id - 640, 16, t);
    else               tconv_tile(W5, T5, 512,  1024, id - 832, 16, t);
}

// ---------------- LayerNorm body ----------------
template <int C>
__device__ __forceinline__ void ln_body(const float* __restrict__ xr,
                                        const float* __restrict__ g,
                                        const float* __restrict__ b,
                                        __bf16* __restrict__ orow,
                                        float* p1, float* p2) {
    constexpr int NP = (C == 1024) ? 4 : 3;
    float v[NP], s1 = 0.f, s2 = 0.f;
    if constexpr (C == 1024) {
        float4 f = *(const float4*)&xr[threadIdx.x * 4];
        v[0] = f.x; v[1] = f.y; v[2] = f.z; v[3] = f.w;
#pragma unroll
        for (int i = 0; i < 4; i++) { s1 += v[i]; s2 += v[i] * v[i]; }
    } else {
#pragma unroll
        for (int i = 0; i < 3; i++) {
            v[i] = xr[threadIdx.x + i * 256];
            s1 += v[i]; s2 += v[i] * v[i];
        }
    }
#pragma unroll
    for (int off = 1; off < 64; off <<= 1) {
        s1 += __shfl_xor(s1, off);
        s2 += __shfl_xor(s2, off);
    }
    int wave = threadIdx.x >> 6;
    if ((threadIdx.x & 63) == 0) { p1[wave] = s1; p2[wave] = s2; }
    __syncthreads();
    s1 = p1[0] + p1[1] + p1[2] + p1[3];
    s2 = p2[0] + p2[1] + p2[2] + p2[3];
    float mean = s1 / C;
    float rstd = rsqrtf(s2 / C - mean * mean + 1e-5f);
    if constexpr (C == 1024) {
        union { __bf16 h[4]; unsigned long long u; } pk;
#pragma unroll
        for (int i = 0; i < 4; i++) {
            int c = threadIdx.x * 4 + i;
            pk.h[i] = (__bf16)((v[i] - mean) * rstd * g[c] + b[c]);
        }
        *(unsigned long long*)&orow[threadIdx.x * 4] = pk.u;
    } else {
#pragma unroll
        for (int i = 0; i < 3; i++) {
            int c = threadIdx.x + i * 256;
            orow[c] = (__bf16)((v[i] - mean) * rstd * g[c] + b[c]);
        }
    }
}

__global__ __launch_bounds__(256) void ln2_kernel(const float* __restrict__ x,
                                                  const float* __restrict__ g1,
                                                  const float* __restrict__ b1,
                                                  const float* __restrict__ g2,
                                                  const float* __restrict__ b2,
                                                  __bf16* __restrict__ o1,
                                                  __bf16* __restrict__ o2) {
    constexpr int C = 1024;
    int row = blockIdx.x;
    const float* xr = x + (size_t)row * C;
    float4 f = *(const float4*)&xr[threadIdx.x * 4];
    float v[4] = {f.x, f.y, f.z, f.w};
    float s1 = 0.f, s2 = 0.f;
#pragma unroll
    for (int i = 0; i < 4; i++) { s1 += v[i]; s2 += v[i] * v[i]; }
#pragma unroll
    for (int off = 1; off < 64; off <<= 1) {
        s1 += __shfl_xor(s1, off);
        s2 += __shfl_xor(s2, off);
    }
    __shared__ float p1[4], p2[4];
    int wave = threadIdx.x >> 6;
    if ((threadIdx.x & 63) == 0) { p1[wave] = s1; p2[wave] = s2; }
    __syncthreads();
    s1 = p1[0] + p1[1] + p1[2] + p1[3];
    s2 = p2[0] + p2[1] + p2[2] + p2[3];
    float mean = s1 / C;
    float rstd = rsqrtf(s2 / C - mean * mean + 1e-5f);
    union { __bf16 h[4]; unsigned long long u; } pk1, pk2;
#pragma unroll
    for (int i = 0; i < 4; i++) {
        int c = threadIdx.x * 4 + i;
        float nv = (v[i] - mean) * rstd;
        pk1.h[i] = (__bf16)(nv * g1[c] + b1[c]);
        pk2.h[i] = (__bf16)(nv * g2[c] + b2[c]);
    }
    *(unsigned long long*)&o1[(size_t)row * C + threadIdx.x * 4] = pk1.u;
    *(unsigned long long*)&o2[(size_t)row * C + threadIdx.x * 4] = pk2.u;
}

__global__ __launch_bounds__(256) void ln_cross_kernel(
    const float* __restrict__ x1, const float* __restrict__ g1, const float* __restrict__ b1,
    __bf16* __restrict__ o1,
    const float* __restrict__ ctx, const float* __restrict__ g2, const float* __restrict__ b2,
    __bf16* __restrict__ o2, int rows1) {
    __shared__ float p1[4], p2[4];
    int id = blockIdx.x;
    if (id < rows1) {
        ln_body<1024>(x1 + (size_t)id * 1024, g1, b1, o1 + (size_t)id * 1024, p1, p2);
    } else {
        int row = id - rows1;
        ln_body<768>(ctx + (size_t)row * 768, g2, b2, o2 + (size_t)row * 768, p1, p2);
    }
}

// ---------------- GEMM core (BK=64): C[M,N] = A[M,K] @ BT[N,K]^T ----------------
template <int EPI>
__device__ __forceinline__ void gemm_core(const __bf16* __restrict__ A,
                                          const __bf16* __restrict__ BT,
                                          void* __restrict__ Cout,
                                          int N, int K, int bm, int bn,
                                          const float* __restrict__ bias,
                                          const float* __restrict__ res,
                                          float scale,
                                          __bf16* Al, __bf16* Bl) {
    int tid = threadIdx.x;
    int lane = tid & 63, wave = tid >> 6;
    int quad = lane >> 4, l15 = lane & 15;
    int wm = wave >> 1, wn = wave & 1;
    const __bf16* Ab = A + (size_t)(bm * 128) * K;
    const __bf16* Bb = BT + (size_t)(bn * 128) * K;
    f32x4 acc[4][4] = {};
    for (int k0 = 0; k0 < K; k0 += 64) {
#pragma unroll
        for (int j = 0; j < 4; j++) {
            int sbase = wave * 256 + j * 64;
            int s = sbase + lane;
            int r = s >> 3, c = (s & 7) ^ (r & 7);
            async16((char*)Al + sbase * 16, &Ab[(size_t)r * K + k0 + c * 8]);
            async16((char*)Bl + sbase * 16, &Bb[(size_t)r * K + k0 + c * 8]);
        }
        __syncthreads();
#pragma unroll
        for (int ks = 0; ks < 2; ks++) {
            bf16x8 a[4], b[4];
#pragma unroll
            for (int i = 0; i < 4; i++) {
                int row = wm * 64 + i * 16 + l15;
                a[i] = *(const bf16x8*)&Al[row * 64 + ((ks * 4 + quad) ^ (row & 7)) * 8];
            }
#pragma unroll
            for (int t = 0; t < 4; t++) {
                int row = wn * 64 + t * 16 + l15;
                b[t] = *(const bf16x8*)&Bl[row * 64 + ((ks * 4 + quad) ^ (row & 7)) * 8];
            }
#pragma unroll
            for (int i = 0; i < 4; i++)
#pragma unroll
                for (int t = 0; t < 4; t++) acc[i][t] = MFMA16(a[i], b[t], acc[i][t]);
        }
        __syncthreads();
    }
#pragma unroll
    for (int i = 0; i < 4; i++) {
#pragma unroll
        for (int t = 0; t < 4; t++) {
#pragma unroll
            for (int r = 0; r < 4; r++) {
                int row = bm * 128 + wm * 64 + i * 16 + quad * 4 + r;
                int col = bn * 128 + wn * 64 + t * 16 + l15;
                float vv = acc[i][t][r];
                if (EPI == 0) {
                    ((__bf16*)Cout)[(size_t)row * N + col] = (__bf16)(vv * scale);
                } else {
                    ((float*)Cout)[(size_t)row * N + col] =
                        vv + bias[col] + res[(size_t)row * N + col];
                }
            }
        }
    }
}

template <int EPI>
__global__ __launch_bounds__(256) void gemm_bt(const __bf16* __restrict__ A,
                                               const __bf16* __restrict__ BT,
                                               void* __restrict__ Cout,
                                               int M, int N, int K,
                                               const float* __restrict__ bias,
                                               const float* __restrict__ res) {
    __shared__ __align__(16) __bf16 Al[128 * 64];
    __shared__ __align__(16) __bf16 Bl[128 * 64];
    gemm_core<EPI>(A, BT, Cout, N, K, blockIdx.x, blockIdx.y, bias, res, 1.0f, Al, Bl);
}

__global__ __launch_bounds__(256) void gemm_fused3(
    const __bf16* A0, const __bf16* B0, __bf16* C0, int N0, int K0, int nbn0, float sc0,
    const __bf16* A1, const __bf16* B1, __bf16* C1, int N1, int K1, int nbn1, float sc1,
    const __bf16* A2, const __bf16* B2, __bf16* C2, int N2, int K2, int nbn2, float sc2,
    int c0, int c1) {
    __shared__ __align__(16) __bf16 Al[128 * 64];
    __shared__ __align__(16) __bf16 Bl[128 * 64];
    int id = blockIdx.x;
    if (id < c0) {
        gemm_core<0>(A0, B0, C0, N0, K0, id / nbn0, id % nbn0, nullptr, nullptr, sc0, Al, Bl);
    } else if (id < c1) {
        id -= c0;
        gemm_core<0>(A1, B1, C1, N1, K1, id / nbn1, id % nbn1, nullptr, nullptr, sc1, Al, Bl);
    } else {
        id -= c1;
        gemm_core<0>(A2, B2, C2, N2, K2, id / nbn2, id % nbn2, nullptr, nullptr, sc2, Al, Bl);
    }
}

// ---------------- flash attention v3: 4-wave blocks, q-tile 128, 32 q-rows/wave ----------------
// q (pre-scaled by 0.125*log2e): [B*n, 512]; kb: [B*m, 512]; vt: [512, B*m]; out: [B*n, 512]
// Wave w owns q rows [32w, 32w+32). St = K@Q^T in 32x32 C-layout:
//   col = q = lane&31; row = kv = 32mt + 4*l5 + (reg&3) + 8*(reg>>2).
// PV B-frag (k=kv=8*l5+j) assembled from St regs via shfl_xor(32) — P never touches LDS.
__global__ __launch_bounds__(256) void flash_kernel(const __bf16* __restrict__ q,
                                                    const __bf16* __restrict__ kb,
                                                    const __bf16* __restrict__ vt,
                                                    __bf16* __restrict__ out,
                                                    int n, int m) {
    __shared__ __align__(16) __bf16 Qs[128 * 64];
    __shared__ __align__(16) __bf16 Ks[64 * 64];
    __shared__ __align__(16) __bf16 VTs[64 * 64];
    int tid = threadIdx.x;
    int lane = tid & 63, w = tid >> 6;      // 4 waves
    int l31 = lane & 31, l5 = lane >> 5;
    int qt = blockIdx.x, h = blockIdx.y, b = blockIdx.z;
    const size_t BM = (size_t)gridDim.z * m;
    const int qrow = w * 32 + l31;

    // stage Q tile 128x64 (16B chunks, chunk c at slot c^(r&7)); 1024 chunks over 256 lanes
#pragma unroll
    for (int j = 0; j < 4; j++) {
        int sbase = j * 256 + w * 64;
        int s = sbase + lane;
        int r = s >> 3, c = (s & 7) ^ (r & 7);
        async16((char*)Qs + sbase * 16,
                &q[(size_t)(b * n + qt * 128 + r) * 512 + h * 64 + c * 8]);
    }

    f32x16 acc[2] = {};    // O^T tiles over d (mtd)
    float l_acc = 0.f;

    int nkt = m / 64;
    for (int kt = 0; kt < nkt; kt++) {
        // stage K/VT 64x64 tiles: 512 chunks each over 256 lanes
#pragma unroll
        for (int j = 0; j < 2; j++) {
            int sbase = j * 256 + w * 64;
            int s = sbase + lane;
            int r = s >> 3, c = (s & 7) ^ (r & 7);
            async16((char*)Ks + sbase * 16,
                    &kb[(size_t)(b * m + kt * 64 + r) * 512 + h * 64 + c * 8]);
            async16((char*)VTs + sbase * 16,
                    &vt[(size_t)(h * 64 + r) * BM + b * m + kt * 64 + c * 8]);
        }
        __syncthreads();

        // ---- QK: St[kv 0..63][q = 32w..+31] over d=64 ----
        bf16x8 bq[4];
#pragma unroll
        for (int c = 0; c < 4; c++)
            bq[c] = *(const bf16x8*)&Qs[qrow * 64 + ((2 * c + l5) ^ (qrow & 7)) * 8];
        f32x16 sacc[2] = {};
#pragma unroll
        for (int mt = 0; mt < 2; mt++) {
            int krow = mt * 32 + l31;
#pragma unroll
            for (int c = 0; c < 4; c++) {
                bf16x8 ak = *(const bf16x8*)&Ks[krow * 64 + ((2 * c + l5) ^ (krow & 7)) * 8];
                sacc[mt] = MFMA32(ak, bq[c], sacc[mt]);
            }
        }

        // ---- exp2, accumulate l, pack bf16, lane<->lane^32 exchange ----
        unsigned long long pk[2][4], sh[2][4];
#pragma unroll
        for (int mt = 0; mt < 2; mt++) {
#pragma unroll
            for (int s = 0; s < 4; s++) {
                float e0 = fast_exp2(sacc[mt][s * 4 + 0]);
                float e1 = fast_exp2(sacc[mt][s * 4 + 1]);
                float e2 = fast_exp2(sacc[mt][s * 4 + 2]);
                float e3 = fast_exp2(sacc[mt][s * 4 + 3]);
                l_acc += (e0 + e1) + (e2 + e3);
                union { __bf16 hh[4]; unsigned long long u; } u;
                u.hh[0] = (__bf16)e0; u.hh[1] = (__bf16)e1;
                u.hh[2] = (__bf16)e2; u.hh[3] = (__bf16)e3;
                pk[mt][s] = u.u;
            }
#pragma unroll
            for (int s = 0; s < 4; s++)
                sh[mt][s] = __shfl_xor((unsigned long long)pk[mt][s], 32);
        }

        // ---- PV: O^T[d][q] += VT[d][kv] * P[kv][q] ----
#pragma unroll
        for (int mt = 0; mt < 2; mt++) {
#pragma unroll
            for (int c2 = 0; c2 < 2; c2++) {
                int s0 = 2 * c2, s1 = 2 * c2 + 1;
                unsigned long long h0 = (l5 == 0) ? pk[mt][s0] : sh[mt][s1];
                unsigned long long h1 = (l5 == 0) ? sh[mt][s0] : pk[mt][s1];
                union { unsigned long long u[2]; bf16x8 v; } bu;
                bu.u[0] = h0; bu.u[1] = h1;
                int kchunk = 2 * (2 * mt + c2) + l5;
#pragma unroll
                for (int mtd = 0; mtd < 2; mtd++) {
                    int drow = mtd * 32 + l31;
                    bf16x8 av = *(const bf16x8*)&VTs[drow * 64 + (kchunk ^ (drow & 7)) * 8];
                    acc[mtd] = MFMA32(av, bu.v, acc[mtd]);
                }
            }
        }
        __syncthreads();
    }

    // finalize: l(q) split across lane pairs (l, l^32)
    float tot = l_acc + __shfl_xor(l_acc, 32);
    float linv = 1.0f / tot;
    size_t qg = (size_t)(b * n + qt * 128 + w * 32 + l31);
#pragma unroll
    for (int mtd = 0; mtd < 2; mtd++) {
#pragma unroll
        for (int s = 0; s < 4; s++) {
            union { __bf16 hh[4]; unsigned long long u; } u;
#pragma unroll
            for (int r = 0; r < 4; r++)
                u.hh[r] = (__bf16)(acc[mtd][s * 4 + r] * linv);
            int d = mtd * 32 + s * 8 + l5 * 4;
            *(unsigned long long*)&out[qg * 512 + h * 64 + d] = u.u;
        }
    }
}

extern "C" void kernel_launch(void* const* d_in, const int* in_sizes, int n_in,
                              void* d_out, int out_size, void* d_ws, size_t ws_size,
                              hipStream_t stream) {
    const float* x      = (const float*)d_in[0];
    const float* ctx    = (const float*)d_in[1];
    const float* sa_ng  = (const float*)d_in[2];
    const float* sa_nb  = (const float*)d_in[3];
    const float* sa_ncg = (const float*)d_in[4];
    const float* sa_ncb = (const float*)d_in[5];
    const float* sa_wq  = (const float*)d_in[6];
    const float* sa_wkv = (const float*)d_in[7];
    const float* sa_wo  = (const float*)d_in[8];
    const float* sa_bo  = (const float*)d_in[9];
    const float* ca_ng  = (const float*)d_in[10];
    const float* ca_nb  = (const float*)d_in[11];
    const float* ca_ncg = (const float*)d_in[12];
    const float* ca_ncb = (const float*)d_in[13];
    const float* ca_wq  = (const float*)d_in[14];
    const float* ca_wkv = (const float*)d_in[15];
    const float* ca_wo  = (const float*)d_in[16];
    const float* ca_bo  = (const float*)d_in[17];
    float* out = (float*)d_out;

    const int B = 4, N = 2048, M = 512, F = 1024, CF = 768, MID = 512;
    const int ROWS = B * N;   // 8192
    const int CROWS = B * M;  // 2048
    const float QSCALE = 0.125f * 1.4426950408889634f;

    char* ws = (char*)d_ws;
    size_t off = 0;
    auto alloc = [&](size_t bytes) {
        void* p = ws + off;
        off = (off + bytes + 255) & ~(size_t)255;
        return p;
    };
    __bf16* wqT   = (__bf16*)alloc((size_t)MID * F * 2);
    __bf16* wkvT  = (__bf16*)alloc((size_t)(2 * MID) * F * 2);
    __bf16* woT   = (__bf16*)alloc((size_t)F * MID * 2);
    __bf16* cwqT  = (__bf16*)alloc((size_t)MID * F * 2);
    __bf16* cwkvT = (__bf16*)alloc((size_t)(2 * MID) * CF * 2);
    __bf16* cwoT  = (__bf16*)alloc((size_t)F * MID * 2);
    __bf16* xn1   = (__bf16*)alloc((size_t)ROWS * F * 2);
    __bf16* xn2   = (__bf16*)alloc((size_t)ROWS * F * 2);
    __bf16* qb    = (__bf16*)alloc((size_t)ROWS * MID * 2);
    __bf16* kb    = (__bf16*)alloc((size_t)ROWS * MID * 2);
    __bf16* vt    = (__bf16*)alloc((size_t)MID * ROWS * 2);
    __bf16* ao    = (__bf16*)alloc((size_t)ROWS * MID * 2);
    float*  x1    = (float*)alloc((size_t)ROWS * F * 4);
    (void)ws_size; (void)in_sizes; (void)n_in; (void)out_size;

    dim3 blk(256);

    tconv6_kernel<<<dim3(960), blk, 0, stream>>>(
        sa_wq, wqT, sa_wkv, wkvT, sa_wo, woT, ca_wq, cwqT, ca_wkv, cwkvT, ca_wo, cwoT);

    // ---- self-attention ----
    ln2_kernel<<<dim3(ROWS), blk, 0, stream>>>(x, sa_ng, sa_nb, sa_ncg, sa_ncb, xn1, xn2);
    {
        int c0 = (ROWS / 128) * (MID / 128);
        int c1 = c0 + (ROWS / 128) * (MID / 128);
        int c2 = c1 + (MID / 128) * (ROWS / 128);
        gemm_fused3<<<dim3(c2), blk, 0, stream>>>(
            xn1, wqT, qb, MID, F, MID / 128, QSCALE,
            xn2, wkvT, kb, MID, F, MID / 128, 1.0f,
            wkvT + (size_t)MID * F, xn2, vt, ROWS, F, ROWS / 128, 1.0f,
            c0, c1);
    }
    flash_kernel<<<dim3(N / 128, 8, B), blk, 0, stream>>>(qb, kb, vt, ao, N, N);
    gemm_bt<1><<<dim3(ROWS / 128, F / 128), blk, 0, stream>>>(
        ao, woT, x1, ROWS, F, MID, sa_bo, x);

    // ---- cross-attention ----
    ln_cross_kernel<<<dim3(ROWS + CROWS), blk, 0, stream>>>(
        x1, ca_ng, ca_nb, xn1, ctx, ca_ncg, ca_ncb, xn2, ROWS);
    {
        int c0 = (ROWS / 128) * (MID / 128);
        int c1 = c0 + (CROWS / 128) * (MID / 128);
        int c2 = c1 + (MID / 128) * (CROWS / 128);
        gemm_fused3<<<dim3(c2), blk, 0, stream>>>(
            xn1, cwqT, qb, MID, F, MID / 128, QSCALE,
            xn2, cwkvT, kb, MID, CF, MID / 128, 1.0f,
            cwkvT + (size_t)MID * CF, xn2, vt, CROWS, CF, CROWS / 128, 1.0f,
            c0, c1);
    }
    flash_kernel<<<dim3(N / 128, 8, B), blk, 0, stream>>>(qb, kb, vt, ao, N, M);
    gemm_bt<1><<<dim3(ROWS / 128, F / 128), blk, 0, stream>>>(
        ao, cwoT, out, ROWS, F, MID, ca_bo, x1);
}